// Round 21
// baseline (469.817 us; speedup 1.0000x reference)
//
#include <hip/hip_runtime.h>

typedef __bf16 bf16;
typedef __bf16 bf16x4 __attribute__((ext_vector_type(4)));
typedef __bf16 bf16x8 __attribute__((ext_vector_type(8)));
typedef float  f32x4  __attribute__((ext_vector_type(4)));

#define DM   1024
#define NH   16
#define DKH  64
#define DFF  4096
#define SEQL 2048
#define NTOK 8192

typedef __attribute__((address_space(1))) void GAS;
typedef __attribute__((address_space(3))) void LAS;

__device__ inline void gload_lds16(const void* g, void* l) {
    __builtin_amdgcn_global_load_lds((GAS*)g, (LAS*)l, 16, 0, 0);
}

// bare v_exp_f32 (exp2) — avoids libm exp2f's range-check sequence
__device__ inline float fast_exp2(float x) {
    float r;
    asm("v_exp_f32 %0, %1" : "=v"(r) : "v"(x));
    return r;
}

// ---------------- cast f32 -> bf16 ----------------
__global__ void cast_f32_bf16(const float* __restrict__ in, bf16* __restrict__ out, long n) {
    long i = ((long)blockIdx.x * 256 + threadIdx.x) * 4;
    long stride = (long)gridDim.x * 256 * 4;
    for (; i < n; i += stride) {
        float4 v = *(const float4*)(in + i);
        bf16x4 o = {(bf16)v.x, (bf16)v.y, (bf16)v.z, (bf16)v.w};
        *(bf16x4*)(out + i) = o;
    }
}

// ---------------- transpose + cast: src[R][C] f32 -> dst[C][R] bf16 ----------------
__global__ void transpose_cast(const float* __restrict__ src, bf16* __restrict__ dst, int R, int C) {
    __shared__ float t[32][33];
    int c0 = blockIdx.x * 32, r0 = blockIdx.y * 32;
    int tx = threadIdx.x, ty = threadIdx.y; // block (32,8)
#pragma unroll
    for (int i = 0; i < 4; ++i)
        t[ty + i * 8][tx] = src[(long)(r0 + ty + i * 8) * C + c0 + tx];
    __syncthreads();
#pragma unroll
    for (int i = 0; i < 4; ++i)
        dst[(long)(c0 + ty + i * 8) * R + r0 + tx] = (bf16)t[tx][ty + i * 8];
}

// ---------------- fused transpose of the four 1024x1024 weights (one launch) ----------------
__global__ void transpose_cast4(const float* __restrict__ s0, const float* __restrict__ s1,
                                const float* __restrict__ s2, const float* __restrict__ s3,
                                bf16* __restrict__ d0, bf16* __restrict__ d1,
                                bf16* __restrict__ d2, bf16* __restrict__ d3) {
    __shared__ float t[32][33];
    const int z = blockIdx.z;
    const float* src = z == 0 ? s0 : z == 1 ? s1 : z == 2 ? s2 : s3;
    bf16* dst = z == 0 ? d0 : z == 1 ? d1 : z == 2 ? d2 : d3;
    int c0 = blockIdx.x * 32, r0 = blockIdx.y * 32;
    int tx = threadIdx.x, ty = threadIdx.y; // block (32,8)
#pragma unroll
    for (int i = 0; i < 4; ++i)
        t[ty + i * 8][tx] = src[(long)(r0 + ty + i * 8) * 1024 + c0 + tx];
    __syncthreads();
#pragma unroll
    for (int i = 0; i < 4; ++i)
        dst[(long)(c0 + ty + i * 8) * 1024 + r0 + tx] = (bf16)t[tx][ty + i * 8];
}

// ---------------- concat 3 bias vectors (1024 each) ----------------
__global__ void concat3(const float* __restrict__ a, const float* __restrict__ b,
                        const float* __restrict__ c, float* __restrict__ out) {
    int i = blockIdx.x * 256 + threadIdx.x;
    if (i < 1024) out[i] = a[i];
    else if (i < 2048) out[i] = b[i - 1024];
    else if (i < 3072) out[i] = c[i - 2048];
}

// ---------------- build V^T: vt[(b*16+h)*64 + d][s] ----------------
__global__ void build_vt(const bf16* __restrict__ qkv, bf16* __restrict__ vt) {
    __shared__ bf16 t[32][33];
    int bh = blockIdx.z, b = bh >> 4, h = bh & 15;
    int s0 = blockIdx.x * 32, d0 = blockIdx.y * 32;
    int tx = threadIdx.x, ty = threadIdx.y;
#pragma unroll
    for (int i = 0; i < 4; ++i)
        t[ty + i * 8][tx] = qkv[(long)(b * SEQL + s0 + ty + i * 8) * 3072 + 2 * DM + h * DKH + d0 + tx];
    __syncthreads();
#pragma unroll
    for (int i = 0; i < 4; ++i)
        vt[((long)bh * DKH + d0 + ty + i * 8) * SEQL + s0 + tx] = (bf16)t[tx][ty + i * 8];
}

// ---------------- GEMM: 4-phase fine interleave + COUNTED vmcnt (r17 best, verbatim) ----------------
// bf16 output only (split-K partials also bf16; summed in fp32 inside add_ln).
template<int BN>
__global__ __launch_bounds__(512, 2)
void gemm4ph(const bf16* __restrict__ A, const bf16* __restrict__ Bt,
             const float* __restrict__ bias,
             bf16* __restrict__ Ch,
             int N, int lda, int Klen, int relu, long strideCh) {
    constexpr int NR = BN / 64;            // 256->4, 192->3
    constexpr int WCOL = BN / 4;           // per-wave N extent
    __shared__ bf16 As[2][8][256][8];      // [buf][kg=k/8][row][8], BK=64
    __shared__ bf16 Bs[2][8][BN][8];
    const int tid = threadIdx.x;
    const int lane = tid & 63;
    const int wv = tid >> 6;
    const int wr = wv >> 2, wc = wv & 3;   // 2 x 4 wave grid
    const int lr = lane & 15, lg = lane >> 4;

    unsigned gx = gridDim.x, gy = gridDim.y;
    unsigned nwg = gx * gy * gridDim.z;
    unsigned wg = (blockIdx.z * gy + blockIdx.y) * gx + blockIdx.x;
    unsigned swz = (wg & 7) * (nwg >> 3) + (wg >> 3);
    unsigned bxi = swz % gx;
    unsigned rem2 = swz / gx;
    unsigned byi = rem2 % gy, bzi = rem2 / gy;

    const long brow = (long)byi * 256;
    const long bcol = (long)bxi * BN;
    const bf16* Ap = A + (long)bzi * Klen;
    const bf16* Bp = Bt + (long)bzi * Klen;
    bf16* Chp = Ch + (long)bzi * strideCh;
    const float* biasp = (bzi == 0) ? bias : nullptr;

    auto stageA = [&](int X, int h) {
        const int kt = X * 64, buf = X & 1;
#pragma unroll
        for (int j = 0; j < 2; ++j) {
            int l = j * 512 + tid;             // cell within half: 0..1023
            int kg = (l >> 8) + h * 4;
            int row = l & 255;
            gload_lds16(Ap + (brow + row) * (long)lda + kt + kg * 8, &As[buf][kg][row][0]);
        }
    };
    auto stageB = [&](int X, int h) {
        const int kt = X * 64, buf = X & 1;
        {
            int l = tid;                       // cells 0..511 of half
            int kg = l / BN + h * 4, row = l % BN;
            gload_lds16(Bp + (bcol + row) * (long)lda + kt + kg * 8, &Bs[buf][kg][row][0]);
        }
        {
            int l = 512 + (BN == 256 ? tid : (tid & 255));  // cells 512..(BN*4-1)
            int kg = l / BN + h * 4, row = l % BN;
            gload_lds16(Bp + (bcol + row) * (long)lda + kt + kg * 8, &Bs[buf][kg][row][0]);
        }
    };

    const int NT = Klen / 64;
    f32x4 acc[8][NR] = {};

    stageA(0, 0); stageB(0, 0); stageA(0, 1); stageB(0, 1);
    asm volatile("s_waitcnt vmcnt(4)" ::: "memory");
    __builtin_amdgcn_s_barrier();
    asm volatile("" ::: "memory");

    for (int T = 0; T < NT; ++T) {
        const int cur = T & 1;
        const bool pf = (T + 1 < NT);
        bf16x8 bv0[NR], bv1[NR], af[4];
        // ---------- ph0 ----------
#pragma unroll
        for (int n = 0; n < NR; ++n)
            bv0[n] = *(const bf16x8*)(&Bs[cur][lg][wc * WCOL + n * 16 + lr][0]);
#pragma unroll
        for (int m = 0; m < 4; ++m)
            af[m] = *(const bf16x8*)(&As[cur][lg][wr * 128 + m * 16 + lr][0]);
        if (pf) stageA(T + 1, 0);
        __builtin_amdgcn_s_barrier();
        asm volatile("s_waitcnt lgkmcnt(0)" ::: "memory");
        __builtin_amdgcn_sched_barrier(0);
        __builtin_amdgcn_s_setprio(1);
#pragma unroll
        for (int m = 0; m < 4; ++m)
#pragma unroll
            for (int n = 0; n < NR; ++n)
                acc[m][n] = __builtin_amdgcn_mfma_f32_16x16x32_bf16(af[m], bv0[n], acc[m][n], 0, 0, 0);
        __builtin_amdgcn_s_setprio(0);
        asm volatile("" ::: "memory");
        __builtin_amdgcn_s_barrier();
        // ---------- ph1 ----------
#pragma unroll
        for (int m = 0; m < 4; ++m)
            af[m] = *(const bf16x8*)(&As[cur][lg][wr * 128 + (4 + m) * 16 + lr][0]);
        if (pf) stageB(T + 1, 0);
        __builtin_amdgcn_s_barrier();
        asm volatile("s_waitcnt lgkmcnt(0)" ::: "memory");
        __builtin_amdgcn_sched_barrier(0);
        __builtin_amdgcn_s_setprio(1);
#pragma unroll
        for (int m = 0; m < 4; ++m)
#pragma unroll
            for (int n = 0; n < NR; ++n)
                acc[4 + m][n] = __builtin_amdgcn_mfma_f32_16x16x32_bf16(af[m], bv0[n], acc[4 + m][n], 0, 0, 0);
        __builtin_amdgcn_s_setprio(0);
        if (pf) asm volatile("s_waitcnt vmcnt(4)" ::: "memory");
        else    asm volatile("s_waitcnt vmcnt(0)" ::: "memory");
        asm volatile("" ::: "memory");
        __builtin_amdgcn_s_barrier();
        // ---------- ph2 ----------
#pragma unroll
        for (int n = 0; n < NR; ++n)
            bv1[n] = *(const bf16x8*)(&Bs[cur][4 + lg][wc * WCOL + n * 16 + lr][0]);
#pragma unroll
        for (int m = 0; m < 4; ++m)
            af[m] = *(const bf16x8*)(&As[cur][4 + lg][wr * 128 + m * 16 + lr][0]);
        if (pf) stageA(T + 1, 1);
        __builtin_amdgcn_s_barrier();
        asm volatile("s_waitcnt lgkmcnt(0)" ::: "memory");
        __builtin_amdgcn_sched_barrier(0);
        __builtin_amdgcn_s_setprio(1);
#pragma unroll
        for (int m = 0; m < 4; ++m)
#pragma unroll
            for (int n = 0; n < NR; ++n)
                acc[m][n] = __builtin_amdgcn_mfma_f32_16x16x32_bf16(af[m], bv1[n], acc[m][n], 0, 0, 0);
        __builtin_amdgcn_s_setprio(0);
        asm volatile("" ::: "memory");
        __builtin_amdgcn_s_barrier();
        // ---------- ph3 ----------
#pragma unroll
        for (int m = 0; m < 4; ++m)
            af[m] = *(const bf16x8*)(&As[cur][4 + lg][wr * 128 + (4 + m) * 16 + lr][0]);
        if (pf) stageB(T + 1, 1);
        __builtin_amdgcn_s_barrier();
        asm volatile("s_waitcnt lgkmcnt(0)" ::: "memory");
        __builtin_amdgcn_sched_barrier(0);
        __builtin_amdgcn_s_setprio(1);
#pragma unroll
        for (int m = 0; m < 4; ++m)
#pragma unroll
            for (int n = 0; n < NR; ++n)
                acc[4 + m][n] = __builtin_amdgcn_mfma_f32_16x16x32_bf16(af[m], bv1[n], acc[4 + m][n], 0, 0, 0);
        __builtin_amdgcn_s_setprio(0);
        if (pf) asm volatile("s_waitcnt vmcnt(4)" ::: "memory");
        asm volatile("" ::: "memory");
        __builtin_amdgcn_s_barrier();
    }

#pragma unroll
    for (int m = 0; m < 8; ++m) {
#pragma unroll
        for (int n = 0; n < NR; ++n) {
            long gcol = bcol + wc * WCOL + n * 16 + lr;
            float bv = biasp ? biasp[gcol] : 0.f;
#pragma unroll
            for (int r = 0; r < 4; ++r) {
                long grow = brow + wr * 128 + m * 16 + lg * 4 + r;
                float v = acc[m][n][r] + bv;
                if (relu) v = v > 0.f ? v : 0.f;
                Chp[grow * N + gcol] = (bf16)v;
            }
        }
    }
}

// ---------------- flash attention (r20 best, verbatim) ----------------
__global__ __launch_bounds__(256, 3)
void attn_fwd(const bf16* __restrict__ qkv, const bf16* __restrict__ vt,
              bf16* __restrict__ attn_o) {
    __shared__ bf16 Ks[2][64][64];   // [buf][kv][d], swizzled
    __shared__ bf16 Vs[2][64][64];   // [buf][d][kv], swizzled
    __shared__ bf16 Plds[4][16][64]; // per-wave P tile [q][kv], swizzled
    const int tid = threadIdx.x, lane = tid & 63, w = tid >> 6;
    const int lr = lane & 15, lg = lane >> 4;

    unsigned nwg = gridDim.x * gridDim.y;       // 1024
    unsigned wg = blockIdx.y * gridDim.x + blockIdx.x;
    unsigned cpx = nwg >> 3;
    unsigned swzid = (wg & 7) * cpx + (wg >> 3);
    const int bx = swzid % gridDim.x, bh = swzid / gridDim.x;
    const int b = bh >> 4, h = bh & 15;
    const int q0 = bx * 128 + w * 32;

    const bf16* Q  = qkv + (long)b * SEQL * 3072 + h * DKH;
    const bf16* Kp = qkv + (long)b * SEQL * 3072 + DM + h * DKH;
    const bf16* Vp = vt + (long)bh * DKH * SEQL;

    const int r0 = w * 8 + (lane >> 3);
    const int cbb = ((lane & 7) * 16) ^ ((r0 & 7) << 4);
    const int cb = cbb >> 1;

    auto stage = [&](int buf, int j0) {
#pragma unroll
        for (int c = 0; c < 2; ++c) {
            bf16* kd = &Ks[buf][0][0] + c * 2048 + w * 512 + lane * 8;
            bf16* vd = &Vs[buf][0][0] + c * 2048 + w * 512 + lane * 8;
            gload_lds16(Kp + (long)(j0 + c * 32 + r0) * 3072 + cb, kd);
            gload_lds16(Vp + (long)(c * 32 + r0) * SEQL + j0 + cb, vd);
        }
    };

    stage(0, 0);

    // Q pre-scale: (1/sqrt(64)) * log2(e) -> scores land in log2 domain
    const float QSC = 0.125f * 1.44269504f;
    bf16x8 aq[2][2];
#pragma unroll
    for (int a = 0; a < 2; ++a)
#pragma unroll
        for (int kh = 0; kh < 2; ++kh) {
            bf16x8 q = *(const bf16x8*)(Q + (long)(q0 + a * 16 + lr) * 3072 + kh * 32 + lg * 8);
#pragma unroll
            for (int e = 0; e < 8; ++e) q[e] = (bf16)((float)q[e] * QSC);
            aq[a][kh] = q;
        }

    float mrow[2] = {-1e30f, -1e30f};
    float lrow[2] = {0.f, 0.f};   // LANE-PARTIAL sums
    f32x4 accO[2][4] = {};
    char* pbase = (char*)&Plds[w][0][0];
    const int psw = (lr & 7) << 4;
    const f32x4 zero = {0.f, 0.f, 0.f, 0.f};
    int cur = 0;

    for (int it = 0; it < SEQL / 64; ++it) {
        if (it < SEQL / 64 - 1) {
            stage(cur ^ 1, (it + 1) * 64);
            asm volatile("s_waitcnt vmcnt(4)" ::: "memory");
        } else {
            asm volatile("s_waitcnt vmcnt(0)" ::: "memory");
        }
        __builtin_amdgcn_s_barrier();
        asm volatile("" ::: "memory");

        const char* Kbuf = (const char*)&Ks[cur][0][0];
        const char* Vbuf = (const char*)&Vs[cur][0][0];

        bf16x8 kf[4][2];
#pragma unroll
        for (int jh = 0; jh < 4; ++jh) {
            int row = jh * 16 + lr;
            int sw = (row & 7) << 4;
            kf[jh][0] = *(const bf16x8*)(Kbuf + row * 128 + ((lg * 16) ^ sw));
            kf[jh][1] = *(const bf16x8*)(Kbuf + row * 128 + ((64 + lg * 16) ^ sw));
        }
        bf16x8 vf[4][2];
#pragma unroll
        for (int c = 0; c < 4; ++c) {
            int row = c * 16 + lr;
            int sw = (row & 7) << 4;
            vf[c][0] = *(const bf16x8*)(Vbuf + row * 128 + ((lg * 16) ^ sw));
            vf[c][1] = *(const bf16x8*)(Vbuf + row * 128 + ((64 + lg * 16) ^ sw));
        }

#pragma unroll
        for (int a = 0; a < 2; ++a) {
            f32x4 s[4];
#pragma unroll
            for (int jh = 0; jh < 4; ++jh) {
                f32x4 t = __builtin_amdgcn_mfma_f32_16x16x32_bf16(kf[jh][0], aq[a][0], zero, 0, 0, 0);
                s[jh] = __builtin_amdgcn_mfma_f32_16x16x32_bf16(kf[jh][1], aq[a][1], t, 0, 0, 0);
            }
            // 16-value max as v_max3 tree
            float a0 = fmaxf(fmaxf(s[0][0], s[0][1]), s[0][2]);
            float a1 = fmaxf(fmaxf(s[0][3], s[1][0]), s[1][1]);
            float a2 = fmaxf(fmaxf(s[1][2], s[1][3]), s[2][0]);
            float a3 = fmaxf(fmaxf(s[2][1], s[2][2]), s[2][3]);
            float a4 = fmaxf(fmaxf(s[3][0], s[3][1]), s[3][2]);
            float b0 = fmaxf(fmaxf(a0, a1), a2);
            float b1 = fmaxf(fmaxf(a3, a4), s[3][3]);
            float pmloc = fmaxf(b0, b1);
            int skip = __all(pmloc - mrow[a] <= 8.0f);
            if (!skip) {
                float pm = fmaxf(pmloc, __shfl_xor(pmloc, 16));
                pm = fmaxf(pm, __shfl_xor(pm, 32));
                float mnew = fmaxf(mrow[a], pm);
                float al = fast_exp2(mrow[a] - mnew);
                mrow[a] = mnew;
                lrow[a] *= al;
                float alr[4];
#pragma unroll
                for (int r = 0; r < 4; ++r)
                    alr[r] = __shfl(al, (lane & 48) | (lg * 4 + r));
#pragma unroll
                for (int c = 0; c < 4; ++c)
#pragma unroll
                    for (int r = 0; r < 4; ++r) accO[a][c][r] *= alr[r];
            }
            float mcur = mrow[a];
            float psum = 0.f;
#pragma unroll
            for (int jh = 0; jh < 4; ++jh)
#pragma unroll
                for (int r = 0; r < 4; ++r) {
                    float p = fast_exp2(s[jh][r] - mcur);
                    s[jh][r] = p;
                    psum += p;
                }
            lrow[a] += psum;
#pragma unroll
            for (int jh = 0; jh < 4; ++jh) {
                bf16x4 pw = {(bf16)s[jh][0], (bf16)s[jh][1], (bf16)s[jh][2], (bf16)s[jh][3]};
                *(bf16x4*)(pbase + lr * 128 + ((jh * 32 + lg * 8) ^ psw)) = pw;
            }
            bf16x8 pa[2];
#pragma unroll
            for (int i = 0; i < 2; ++i)
                pa[i] = *(const bf16x8*)(pbase + lr * 128 + ((i * 64 + lg * 16) ^ psw));
#pragma unroll
            for (int c = 0; c < 4; ++c) {
                accO[a][c] = __builtin_amdgcn_mfma_f32_16x16x32_bf16(pa[0], vf[c][0], accO[a][c], 0, 0, 0);
                accO[a][c] = __builtin_amdgcn_mfma_f32_16x16x32_bf16(pa[1], vf[c][1], accO[a][c], 0, 0, 0);
            }
        }
        asm volatile("" ::: "memory");
        __builtin_amdgcn_s_barrier();
        cur ^= 1;
    }

#pragma unroll
    for (int a = 0; a < 2; ++a) {
        float lsum = lrow[a];
        lsum += __shfl_xor(lsum, 16);
        lsum += __shfl_xor(lsum, 32);
        float linv = 1.0f / lsum;
        float invr[4];
#pragma unroll
        for (int r = 0; r < 4; ++r)
            invr[r] = __shfl(linv, (lane & 48) | (lg * 4 + r));
#pragma unroll
        for (int r = 0; r < 4; ++r) {
            long grow = (long)b * SEQL + q0 + a * 16 + lg * 4 + r;
#pragma unroll
            for (int c = 0; c < 4; ++c)
                attn_o[grow * DM + h * DKH + c * 16 + lr] = (bf16)(accO[a][c][r] * invr[r]);
        }
    }
}

// ---------------- fused residual add (NP bf16 partials) + LayerNorm ----------------
// AISF32: residual dtype (1 = fp32, 0 = bf16). NP = number of split-K partials,
// stored contiguously at Bp + k*NTOK*DM. Summed in fp32.
template<int AISF32, int NP>
__global__ __launch_bounds__(256)
void add_ln(const void* __restrict__ Ap, const bf16* __restrict__ Bp,
            const float* __restrict__ g, const float* __restrict__ be,
            float* __restrict__ outf, bf16* __restrict__ outh) {
    const int w = threadIdx.x >> 6, lane = threadIdx.x & 63;
    const long row = (long)blockIdx.x * 4 + w;
    float4 v[4];
    float s = 0.f;
#pragma unroll
    for (int i = 0; i < 4; ++i) {
        int sl = i * 64 + lane;
        float4 a;
        if (AISF32) {
            a = ((const float4*)((const float*)Ap + row * DM))[sl];
        } else {
            bf16x4 ah = ((const bf16x4*)((const bf16*)Ap + row * DM))[sl];
            a = make_float4((float)ah[0], (float)ah[1], (float)ah[2], (float)ah[3]);
        }
        v[i] = a;
#pragma unroll
        for (int k = 0; k < NP; ++k) {
            bf16x4 bh = ((const bf16x4*)(Bp + (long)k * NTOK * DM + row * DM))[sl];
            v[i].x += (float)bh[0]; v[i].y += (float)bh[1];
            v[i].z += (float)bh[2]; v[i].w += (float)bh[3];
        }
        s += v[i].x + v[i].y + v[i].z + v[i].w;
    }
#pragma unroll
    for (int off = 32; off; off >>= 1) s += __shfl_xor(s, off);
    float mu = s * (1.0f / 1024.0f);
    float var = 0.f;
#pragma unroll
    for (int i = 0; i < 4; ++i) {
        float dx = v[i].x - mu, dy = v[i].y - mu, dz = v[i].z - mu, dw = v[i].w - mu;
        var += dx * dx + dy * dy + dz * dz + dw * dw;
    }
#pragma unroll
    for (int off = 32; off; off >>= 1) var += __shfl_xor(var, off);
    float rs = 1.0f / sqrtf(var * (1.0f / 1024.0f) + 1e-5f);
    const float4* pg = (const float4*)g;
    const float4* pe = (const float4*)be;
#pragma unroll
    for (int i = 0; i < 4; ++i) {
        float4 gg = pg[i * 64 + lane], ee = pe[i * 64 + lane];
        float4 o = make_float4((v[i].x - mu) * rs * gg.x + ee.x,
                               (v[i].y - mu) * rs * gg.y + ee.y,
                               (v[i].z - mu) * rs * gg.z + ee.z,
                               (v[i].w - mu) * rs * gg.w + ee.w);
        if (outf) ((float4*)(outf + row * DM))[i * 64 + lane] = o;
        if (outh) {
            bf16x4 ho = {(bf16)o.x, (bf16)o.y, (bf16)o.z, (bf16)o.w};
            *(bf16x4*)(outh + row * DM + (i * 64 + lane) * 4) = ho;
        }
    }
}

extern "C" void kernel_launch(void* const* d_in, const int* in_sizes, int n_in,
                              void* d_out, int out_size, void* d_ws, size_t ws_size,
                              hipStream_t stream) {
    const float* x   = (const float*)d_in[0];
    const float* Wq  = (const float*)d_in[1];
    const float* bq  = (const float*)d_in[2];
    const float* Wk  = (const float*)d_in[3];
    const float* bk  = (const float*)d_in[4];
    const float* Wv  = (const float*)d_in[5];
    const float* bv  = (const float*)d_in[6];
    const float* Wo  = (const float*)d_in[7];
    const float* bo  = (const float*)d_in[8];
    const float* W1  = (const float*)d_in[9];
    const float* b1  = (const float*)d_in[10];
    const float* W2  = (const float*)d_in[11];
    const float* b2  = (const float*)d_in[12];
    const float* g1  = (const float*)d_in[13];
    const float* be1 = (const float*)d_in[14];
    const float* g2  = (const float*)d_in[15];
    const float* be2 = (const float*)d_in[16];
    float* out = (float*)d_out;

    char* ws = (char*)d_ws;
    size_t off = 0;
    auto alloc = [&](size_t bytes) {
        void* p = ws + off;
        off += (bytes + 255) & ~(size_t)255;
        return p;
    };
    bf16* xh    = (bf16*)alloc((size_t)NTOK * DM * 2);
    bf16* wqkvt = (bf16*)alloc((size_t)3072 * 1024 * 2);
    bf16* wot   = (bf16*)alloc((size_t)1024 * 1024 * 2);
    bf16* w1t   = (bf16*)alloc((size_t)4096 * 1024 * 2);
    bf16* w2t   = (bf16*)alloc((size_t)1024 * 4096 * 2);
    float* bqkv = (float*)alloc((size_t)3072 * 4);
    bf16* qkv   = (bf16*)alloc((size_t)NTOK * 3072 * 2);
    bf16* vtb   = (bf16*)alloc((size_t)NTOK * DM * 2);
    bf16* attno = (bf16*)alloc((size_t)NTOK * DM * 2);
    bf16* projs = (bf16*)alloc((size_t)4 * NTOK * DM * 2);  // split-K partials 0..3 (bf16, contiguous)
    bf16* x1h   = (bf16*)alloc((size_t)NTOK * DM * 2);   // LN1 out = FFN1 in = LN2 residual
    bf16* ffh   = (bf16*)qkv; // alias: qkv+vtb dead after attn; 67MB for [8192][4096]

    dim3 tb(32, 8);
    cast_f32_bf16<<<2048, 256, 0, stream>>>(x, xh, (long)NTOK * DM);
    // fused: Wq/Wk/Wv -> wqkvt slices, Wo -> wot (one launch, grid z=4)
    transpose_cast4<<<dim3(32, 32, 4), tb, 0, stream>>>(
        Wq, Wk, Wv, Wo,
        wqkvt, wqkvt + (size_t)1024 * 1024, wqkvt + (size_t)2048 * 1024, wot);
    transpose_cast<<<dim3(128, 32), tb, 0, stream>>>(W1, w1t, 1024, 4096);
    transpose_cast<<<dim3(32, 128), tb, 0, stream>>>(W2, w2t, 4096, 1024);
    concat3<<<12, 256, 0, stream>>>(bq, bk, bv, bqkv);

    // QKV: [8192,1024]@[1024,3072] -> bf16 (BN=192: grid 16x32=512 = 2 even rounds)
    gemm4ph<192><<<dim3(3072 / 192, 8192 / 256, 1), 512, 0, stream>>>(
        xh, wqkvt, bqkv, qkv, 3072, 1024, 1024, 0, 0);
    build_vt<<<dim3(SEQL / 32, 2, 64), tb, 0, stream>>>(qkv, vtb);
    attn_fwd<<<dim3(SEQL / 128, 64), 256, 0, stream>>>(qkv, vtb, attno);
    // Wo: split-K x2 (Klen=512), grid 4x32x2=256 -> bf16 partials projs[0..1]
    gemm4ph<256><<<dim3(1024 / 256, 8192 / 256, 2), 512, 0, stream>>>(
        attno, wot, bo, projs, 1024, 1024, 512, 0, (long)NTOK * DM);
    add_ln<1, 2><<<NTOK / 4, 256, 0, stream>>>(x, projs, g1, be1, nullptr, x1h);
    // FFN1: [8192,1024]@[1024,4096]+ReLU -> bf16 (grid 16x32=512)
    gemm4ph<256><<<dim3(4096 / 256, 8192 / 256, 1), 512, 0, stream>>>(
        x1h, w1t, b1, ffh, 4096, 1024, 1024, 1, 0);
    // FFN2: split-K x4 (Klen=1024), grid 4x32x4=512 = 2 even rounds -> projs[0..3]
    gemm4ph<256><<<dim3(1024 / 256, 8192 / 256, 4), 512, 0, stream>>>(
        ffh, w2t, b2, projs, 1024, 4096, 1024, 0, (long)NTOK * DM);
    add_ln<0, 4><<<NTOK / 4, 256, 0, stream>>>(x1h, projs, g2, be2, out, nullptr);
}

// Round 22
// 454.001 us; speedup vs baseline: 1.0348x; 1.0348x over previous
//
#include <hip/hip_runtime.h>

typedef __bf16 bf16;
typedef __bf16 bf16x4 __attribute__((ext_vector_type(4)));
typedef __bf16 bf16x8 __attribute__((ext_vector_type(8)));
typedef float  f32x4  __attribute__((ext_vector_type(4)));

#define DM   1024
#define NH   16
#define DKH  64
#define DFF  4096
#define SEQL 2048
#define NTOK 8192

typedef __attribute__((address_space(1))) void GAS;
typedef __attribute__((address_space(3))) void LAS;

__device__ inline void gload_lds16(const void* g, void* l) {
    __builtin_amdgcn_global_load_lds((GAS*)g, (LAS*)l, 16, 0, 0);
}

// bare v_exp_f32 (exp2) — avoids libm exp2f's range-check sequence
__device__ inline float fast_exp2(float x) {
    float r;
    asm("v_exp_f32 %0, %1" : "=v"(r) : "v"(x));
    return r;
}

// ---------------- cast f32 -> bf16 ----------------
__global__ void cast_f32_bf16(const float* __restrict__ in, bf16* __restrict__ out, long n) {
    long i = ((long)blockIdx.x * 256 + threadIdx.x) * 4;
    long stride = (long)gridDim.x * 256 * 4;
    for (; i < n; i += stride) {
        float4 v = *(const float4*)(in + i);
        bf16x4 o = {(bf16)v.x, (bf16)v.y, (bf16)v.z, (bf16)v.w};
        *(bf16x4*)(out + i) = o;
    }
}

// ---------------- transpose + cast: src[R][C] f32 -> dst[C][R] bf16 ----------------
__global__ void transpose_cast(const float* __restrict__ src, bf16* __restrict__ dst, int R, int C) {
    __shared__ float t[32][33];
    int c0 = blockIdx.x * 32, r0 = blockIdx.y * 32;
    int tx = threadIdx.x, ty = threadIdx.y; // block (32,8)
#pragma unroll
    for (int i = 0; i < 4; ++i)
        t[ty + i * 8][tx] = src[(long)(r0 + ty + i * 8) * C + c0 + tx];
    __syncthreads();
#pragma unroll
    for (int i = 0; i < 4; ++i)
        dst[(long)(c0 + ty + i * 8) * R + r0 + tx] = (bf16)t[tx][ty + i * 8];
}

// ---------------- fused transpose of the four 1024x1024 weights (one launch) ----------------
__global__ void transpose_cast4(const float* __restrict__ s0, const float* __restrict__ s1,
                                const float* __restrict__ s2, const float* __restrict__ s3,
                                bf16* __restrict__ d0, bf16* __restrict__ d1,
                                bf16* __restrict__ d2, bf16* __restrict__ d3) {
    __shared__ float t[32][33];
    const int z = blockIdx.z;
    const float* src = z == 0 ? s0 : z == 1 ? s1 : z == 2 ? s2 : s3;
    bf16* dst = z == 0 ? d0 : z == 1 ? d1 : z == 2 ? d2 : d3;
    int c0 = blockIdx.x * 32, r0 = blockIdx.y * 32;
    int tx = threadIdx.x, ty = threadIdx.y; // block (32,8)
#pragma unroll
    for (int i = 0; i < 4; ++i)
        t[ty + i * 8][tx] = src[(long)(r0 + ty + i * 8) * 1024 + c0 + tx];
    __syncthreads();
#pragma unroll
    for (int i = 0; i < 4; ++i)
        dst[(long)(c0 + ty + i * 8) * 1024 + r0 + tx] = (bf16)t[tx][ty + i * 8];
}

// ---------------- concat 3 bias vectors (1024 each) ----------------
__global__ void concat3(const float* __restrict__ a, const float* __restrict__ b,
                        const float* __restrict__ c, float* __restrict__ out) {
    int i = blockIdx.x * 256 + threadIdx.x;
    if (i < 1024) out[i] = a[i];
    else if (i < 2048) out[i] = b[i - 1024];
    else if (i < 3072) out[i] = c[i - 2048];
}

// ---------------- build V^T: vt[(b*16+h)*64 + d][s] ----------------
__global__ void build_vt(const bf16* __restrict__ qkv, bf16* __restrict__ vt) {
    __shared__ bf16 t[32][33];
    int bh = blockIdx.z, b = bh >> 4, h = bh & 15;
    int s0 = blockIdx.x * 32, d0 = blockIdx.y * 32;
    int tx = threadIdx.x, ty = threadIdx.y;
#pragma unroll
    for (int i = 0; i < 4; ++i)
        t[ty + i * 8][tx] = qkv[(long)(b * SEQL + s0 + ty + i * 8) * 3072 + 2 * DM + h * DKH + d0 + tx];
    __syncthreads();
#pragma unroll
    for (int i = 0; i < 4; ++i)
        vt[((long)bh * DKH + d0 + ty + i * 8) * SEQL + s0 + tx] = (bf16)t[tx][ty + i * 8];
}

// ---------------- GEMM: 4-phase fine interleave + COUNTED vmcnt (r17 best, verbatim) ----------------
// bf16 output only (split-K partials also bf16; summed in fp32 inside add_ln).
template<int BN>
__global__ __launch_bounds__(512, 2)
void gemm4ph(const bf16* __restrict__ A, const bf16* __restrict__ Bt,
             const float* __restrict__ bias,
             bf16* __restrict__ Ch,
             int N, int lda, int Klen, int relu, long strideCh) {
    constexpr int NR = BN / 64;            // 256->4, 192->3
    constexpr int WCOL = BN / 4;           // per-wave N extent
    __shared__ bf16 As[2][8][256][8];      // [buf][kg=k/8][row][8], BK=64
    __shared__ bf16 Bs[2][8][BN][8];
    const int tid = threadIdx.x;
    const int lane = tid & 63;
    const int wv = tid >> 6;
    const int wr = wv >> 2, wc = wv & 3;   // 2 x 4 wave grid
    const int lr = lane & 15, lg = lane >> 4;

    unsigned gx = gridDim.x, gy = gridDim.y;
    unsigned nwg = gx * gy * gridDim.z;
    unsigned wg = (blockIdx.z * gy + blockIdx.y) * gx + blockIdx.x;
    unsigned swz = (wg & 7) * (nwg >> 3) + (wg >> 3);
    unsigned bxi = swz % gx;
    unsigned rem2 = swz / gx;
    unsigned byi = rem2 % gy, bzi = rem2 / gy;

    const long brow = (long)byi * 256;
    const long bcol = (long)bxi * BN;
    const bf16* Ap = A + (long)bzi * Klen;
    const bf16* Bp = Bt + (long)bzi * Klen;
    bf16* Chp = Ch + (long)bzi * strideCh;
    const float* biasp = (bzi == 0) ? bias : nullptr;

    auto stageA = [&](int X, int h) {
        const int kt = X * 64, buf = X & 1;
#pragma unroll
        for (int j = 0; j < 2; ++j) {
            int l = j * 512 + tid;             // cell within half: 0..1023
            int kg = (l >> 8) + h * 4;
            int row = l & 255;
            gload_lds16(Ap + (brow + row) * (long)lda + kt + kg * 8, &As[buf][kg][row][0]);
        }
    };
    auto stageB = [&](int X, int h) {
        const int kt = X * 64, buf = X & 1;
        {
            int l = tid;                       // cells 0..511 of half
            int kg = l / BN + h * 4, row = l % BN;
            gload_lds16(Bp + (bcol + row) * (long)lda + kt + kg * 8, &Bs[buf][kg][row][0]);
        }
        {
            int l = 512 + (BN == 256 ? tid : (tid & 255));  // cells 512..(BN*4-1)
            int kg = l / BN + h * 4, row = l % BN;
            gload_lds16(Bp + (bcol + row) * (long)lda + kt + kg * 8, &Bs[buf][kg][row][0]);
        }
    };

    const int NT = Klen / 64;
    f32x4 acc[8][NR] = {};

    stageA(0, 0); stageB(0, 0); stageA(0, 1); stageB(0, 1);
    asm volatile("s_waitcnt vmcnt(4)" ::: "memory");
    __builtin_amdgcn_s_barrier();
    asm volatile("" ::: "memory");

    for (int T = 0; T < NT; ++T) {
        const int cur = T & 1;
        const bool pf = (T + 1 < NT);
        bf16x8 bv0[NR], bv1[NR], af[4];
        // ---------- ph0 ----------
#pragma unroll
        for (int n = 0; n < NR; ++n)
            bv0[n] = *(const bf16x8*)(&Bs[cur][lg][wc * WCOL + n * 16 + lr][0]);
#pragma unroll
        for (int m = 0; m < 4; ++m)
            af[m] = *(const bf16x8*)(&As[cur][lg][wr * 128 + m * 16 + lr][0]);
        if (pf) stageA(T + 1, 0);
        __builtin_amdgcn_s_barrier();
        asm volatile("s_waitcnt lgkmcnt(0)" ::: "memory");
        __builtin_amdgcn_sched_barrier(0);
        __builtin_amdgcn_s_setprio(1);
#pragma unroll
        for (int m = 0; m < 4; ++m)
#pragma unroll
            for (int n = 0; n < NR; ++n)
                acc[m][n] = __builtin_amdgcn_mfma_f32_16x16x32_bf16(af[m], bv0[n], acc[m][n], 0, 0, 0);
        __builtin_amdgcn_s_setprio(0);
        asm volatile("" ::: "memory");
        __builtin_amdgcn_s_barrier();
        // ---------- ph1 ----------
#pragma unroll
        for (int m = 0; m < 4; ++m)
            af[m] = *(const bf16x8*)(&As[cur][lg][wr * 128 + (4 + m) * 16 + lr][0]);
        if (pf) stageB(T + 1, 0);
        __builtin_amdgcn_s_barrier();
        asm volatile("s_waitcnt lgkmcnt(0)" ::: "memory");
        __builtin_amdgcn_sched_barrier(0);
        __builtin_amdgcn_s_setprio(1);
#pragma unroll
        for (int m = 0; m < 4; ++m)
#pragma unroll
            for (int n = 0; n < NR; ++n)
                acc[4 + m][n] = __builtin_amdgcn_mfma_f32_16x16x32_bf16(af[m], bv0[n], acc[4 + m][n], 0, 0, 0);
        __builtin_amdgcn_s_setprio(0);
        if (pf) asm volatile("s_waitcnt vmcnt(4)" ::: "memory");
        else    asm volatile("s_waitcnt vmcnt(0)" ::: "memory");
        asm volatile("" ::: "memory");
        __builtin_amdgcn_s_barrier();
        // ---------- ph2 ----------
#pragma unroll
        for (int n = 0; n < NR; ++n)
            bv1[n] = *(const bf16x8*)(&Bs[cur][4 + lg][wc * WCOL + n * 16 + lr][0]);
#pragma unroll
        for (int m = 0; m < 4; ++m)
            af[m] = *(const bf16x8*)(&As[cur][4 + lg][wr * 128 + m * 16 + lr][0]);
        if (pf) stageA(T + 1, 1);
        __builtin_amdgcn_s_barrier();
        asm volatile("s_waitcnt lgkmcnt(0)" ::: "memory");
        __builtin_amdgcn_sched_barrier(0);
        __builtin_amdgcn_s_setprio(1);
#pragma unroll
        for (int m = 0; m < 4; ++m)
#pragma unroll
            for (int n = 0; n < NR; ++n)
                acc[m][n] = __builtin_amdgcn_mfma_f32_16x16x32_bf16(af[m], bv1[n], acc[m][n], 0, 0, 0);
        __builtin_amdgcn_s_setprio(0);
        asm volatile("" ::: "memory");
        __builtin_amdgcn_s_barrier();
        // ---------- ph3 ----------
#pragma unroll
        for (int m = 0; m < 4; ++m)
            af[m] = *(const bf16x8*)(&As[cur][4 + lg][wr * 128 + (4 + m) * 16 + lr][0]);
        if (pf) stageB(T + 1, 1);
        __builtin_amdgcn_s_barrier();
        asm volatile("s_waitcnt lgkmcnt(0)" ::: "memory");
        __builtin_amdgcn_sched_barrier(0);
        __builtin_amdgcn_s_setprio(1);
#pragma unroll
        for (int m = 0; m < 4; ++m)
#pragma unroll
            for (int n = 0; n < NR; ++n)
                acc[4 + m][n] = __builtin_amdgcn_mfma_f32_16x16x32_bf16(af[m], bv1[n], acc[4 + m][n], 0, 0, 0);
        __builtin_amdgcn_s_setprio(0);
        if (pf) asm volatile("s_waitcnt vmcnt(4)" ::: "memory");
        asm volatile("" ::: "memory");
        __builtin_amdgcn_s_barrier();
    }

#pragma unroll
    for (int m = 0; m < 8; ++m) {
#pragma unroll
        for (int n = 0; n < NR; ++n) {
            long gcol = bcol + wc * WCOL + n * 16 + lr;
            float bv = biasp ? biasp[gcol] : 0.f;
#pragma unroll
            for (int r = 0; r < 4; ++r) {
                long grow = brow + wr * 128 + m * 16 + lg * 4 + r;
                float v = acc[m][n][r] + bv;
                if (relu) v = v > 0.f ? v : 0.f;
                Chp[grow * N + gcol] = (bf16)v;
            }
        }
    }
}

// ---------------- flash attention (r20 best, verbatim) ----------------
__global__ __launch_bounds__(256, 3)
void attn_fwd(const bf16* __restrict__ qkv, const bf16* __restrict__ vt,
              bf16* __restrict__ attn_o) {
    __shared__ bf16 Ks[2][64][64];   // [buf][kv][d], swizzled
    __shared__ bf16 Vs[2][64][64];   // [buf][d][kv], swizzled
    __shared__ bf16 Plds[4][16][64]; // per-wave P tile [q][kv], swizzled
    const int tid = threadIdx.x, lane = tid & 63, w = tid >> 6;
    const int lr = lane & 15, lg = lane >> 4;

    unsigned nwg = gridDim.x * gridDim.y;       // 1024
    unsigned wg = blockIdx.y * gridDim.x + blockIdx.x;
    unsigned cpx = nwg >> 3;
    unsigned swzid = (wg & 7) * cpx + (wg >> 3);
    const int bx = swzid % gridDim.x, bh = swzid / gridDim.x;
    const int b = bh >> 4, h = bh & 15;
    const int q0 = bx * 128 + w * 32;

    const bf16* Q  = qkv + (long)b * SEQL * 3072 + h * DKH;
    const bf16* Kp = qkv + (long)b * SEQL * 3072 + DM + h * DKH;
    const bf16* Vp = vt + (long)bh * DKH * SEQL;

    const int r0 = w * 8 + (lane >> 3);
    const int cbb = ((lane & 7) * 16) ^ ((r0 & 7) << 4);
    const int cb = cbb >> 1;

    auto stage = [&](int buf, int j0) {
#pragma unroll
        for (int c = 0; c < 2; ++c) {
            bf16* kd = &Ks[buf][0][0] + c * 2048 + w * 512 + lane * 8;
            bf16* vd = &Vs[buf][0][0] + c * 2048 + w * 512 + lane * 8;
            gload_lds16(Kp + (long)(j0 + c * 32 + r0) * 3072 + cb, kd);
            gload_lds16(Vp + (long)(c * 32 + r0) * SEQL + j0 + cb, vd);
        }
    };

    stage(0, 0);

    // Q pre-scale: (1/sqrt(64)) * log2(e) -> scores land in log2 domain
    const float QSC = 0.125f * 1.44269504f;
    bf16x8 aq[2][2];
#pragma unroll
    for (int a = 0; a < 2; ++a)
#pragma unroll
        for (int kh = 0; kh < 2; ++kh) {
            bf16x8 q = *(const bf16x8*)(Q + (long)(q0 + a * 16 + lr) * 3072 + kh * 32 + lg * 8);
#pragma unroll
            for (int e = 0; e < 8; ++e) q[e] = (bf16)((float)q[e] * QSC);
            aq[a][kh] = q;
        }

    float mrow[2] = {-1e30f, -1e30f};
    float lrow[2] = {0.f, 0.f};   // LANE-PARTIAL sums
    f32x4 accO[2][4] = {};
    char* pbase = (char*)&Plds[w][0][0];
    const int psw = (lr & 7) << 4;
    const f32x4 zero = {0.f, 0.f, 0.f, 0.f};
    int cur = 0;

    for (int it = 0; it < SEQL / 64; ++it) {
        if (it < SEQL / 64 - 1) {
            stage(cur ^ 1, (it + 1) * 64);
            asm volatile("s_waitcnt vmcnt(4)" ::: "memory");
        } else {
            asm volatile("s_waitcnt vmcnt(0)" ::: "memory");
        }
        __builtin_amdgcn_s_barrier();
        asm volatile("" ::: "memory");

        const char* Kbuf = (const char*)&Ks[cur][0][0];
        const char* Vbuf = (const char*)&Vs[cur][0][0];

        bf16x8 kf[4][2];
#pragma unroll
        for (int jh = 0; jh < 4; ++jh) {
            int row = jh * 16 + lr;
            int sw = (row & 7) << 4;
            kf[jh][0] = *(const bf16x8*)(Kbuf + row * 128 + ((lg * 16) ^ sw));
            kf[jh][1] = *(const bf16x8*)(Kbuf + row * 128 + ((64 + lg * 16) ^ sw));
        }
        bf16x8 vf[4][2];
#pragma unroll
        for (int c = 0; c < 4; ++c) {
            int row = c * 16 + lr;
            int sw = (row & 7) << 4;
            vf[c][0] = *(const bf16x8*)(Vbuf + row * 128 + ((lg * 16) ^ sw));
            vf[c][1] = *(const bf16x8*)(Vbuf + row * 128 + ((64 + lg * 16) ^ sw));
        }

#pragma unroll
        for (int a = 0; a < 2; ++a) {
            f32x4 s[4];
#pragma unroll
            for (int jh = 0; jh < 4; ++jh) {
                f32x4 t = __builtin_amdgcn_mfma_f32_16x16x32_bf16(kf[jh][0], aq[a][0], zero, 0, 0, 0);
                s[jh] = __builtin_amdgcn_mfma_f32_16x16x32_bf16(kf[jh][1], aq[a][1], t, 0, 0, 0);
            }
            // 16-value max as v_max3 tree
            float a0 = fmaxf(fmaxf(s[0][0], s[0][1]), s[0][2]);
            float a1 = fmaxf(fmaxf(s[0][3], s[1][0]), s[1][1]);
            float a2 = fmaxf(fmaxf(s[1][2], s[1][3]), s[2][0]);
            float a3 = fmaxf(fmaxf(s[2][1], s[2][2]), s[2][3]);
            float a4 = fmaxf(fmaxf(s[3][0], s[3][1]), s[3][2]);
            float b0 = fmaxf(fmaxf(a0, a1), a2);
            float b1 = fmaxf(fmaxf(a3, a4), s[3][3]);
            float pmloc = fmaxf(b0, b1);
            int skip = __all(pmloc - mrow[a] <= 8.0f);
            if (!skip) {
                float pm = fmaxf(pmloc, __shfl_xor(pmloc, 16));
                pm = fmaxf(pm, __shfl_xor(pm, 32));
                float mnew = fmaxf(mrow[a], pm);
                float al = fast_exp2(mrow[a] - mnew);
                mrow[a] = mnew;
                lrow[a] *= al;
                float alr[4];
#pragma unroll
                for (int r = 0; r < 4; ++r)
                    alr[r] = __shfl(al, (lane & 48) | (lg * 4 + r));
#pragma unroll
                for (int c = 0; c < 4; ++c)
#pragma unroll
                    for (int r = 0; r < 4; ++r) accO[a][c][r] *= alr[r];
            }
            float mcur = mrow[a];
            float psum = 0.f;
#pragma unroll
            for (int jh = 0; jh < 4; ++jh)
#pragma unroll
                for (int r = 0; r < 4; ++r) {
                    float p = fast_exp2(s[jh][r] - mcur);
                    s[jh][r] = p;
                    psum += p;
                }
            lrow[a] += psum;
#pragma unroll
            for (int jh = 0; jh < 4; ++jh) {
                bf16x4 pw = {(bf16)s[jh][0], (bf16)s[jh][1], (bf16)s[jh][2], (bf16)s[jh][3]};
                *(bf16x4*)(pbase + lr * 128 + ((jh * 32 + lg * 8) ^ psw)) = pw;
            }
            bf16x8 pa[2];
#pragma unroll
            for (int i = 0; i < 2; ++i)
                pa[i] = *(const bf16x8*)(pbase + lr * 128 + ((i * 64 + lg * 16) ^ psw));
#pragma unroll
            for (int c = 0; c < 4; ++c) {
                accO[a][c] = __builtin_amdgcn_mfma_f32_16x16x32_bf16(pa[0], vf[c][0], accO[a][c], 0, 0, 0);
                accO[a][c] = __builtin_amdgcn_mfma_f32_16x16x32_bf16(pa[1], vf[c][1], accO[a][c], 0, 0, 0);
            }
        }
        asm volatile("" ::: "memory");
        __builtin_amdgcn_s_barrier();
        cur ^= 1;
    }

#pragma unroll
    for (int a = 0; a < 2; ++a) {
        float lsum = lrow[a];
        lsum += __shfl_xor(lsum, 16);
        lsum += __shfl_xor(lsum, 32);
        float linv = 1.0f / lsum;
        float invr[4];
#pragma unroll
        for (int r = 0; r < 4; ++r)
            invr[r] = __shfl(linv, (lane & 48) | (lg * 4 + r));
#pragma unroll
        for (int r = 0; r < 4; ++r) {
            long grow = (long)b * SEQL + q0 + a * 16 + lg * 4 + r;
#pragma unroll
            for (int c = 0; c < 4; ++c)
                attn_o[grow * DM + h * DKH + c * 16 + lr] = (bf16)(accO[a][c][r] * invr[r]);
        }
    }
}

// ---------------- fused residual add (bf16 partials) + LayerNorm ----------------
// AISF32: residual dtype (1 = fp32 [x], 0 = bf16 [x1h]). B,B2 = bf16 split-K
// partials summed in fp32. Outputs: fp32 (final) and/or bf16.
template<int AISF32>
__global__ __launch_bounds__(256)
void add_ln(const void* __restrict__ Ap, const bf16* __restrict__ B,
            const bf16* __restrict__ B2,
            const float* __restrict__ g, const float* __restrict__ be,
            float* __restrict__ outf, bf16* __restrict__ outh) {
    const int w = threadIdx.x >> 6, lane = threadIdx.x & 63;
    const long row = (long)blockIdx.x * 4 + w;
    float4 v[4];
    float s = 0.f;
#pragma unroll
    for (int i = 0; i < 4; ++i) {
        int sl = i * 64 + lane;
        float4 a;
        if (AISF32) {
            a = ((const float4*)((const float*)Ap + row * DM))[sl];
        } else {
            bf16x4 ah = ((const bf16x4*)((const bf16*)Ap + row * DM))[sl];
            a = make_float4((float)ah[0], (float)ah[1], (float)ah[2], (float)ah[3]);
        }
        bf16x4 bh = ((const bf16x4*)(B + row * DM))[sl];
        bf16x4 b2h = ((const bf16x4*)(B2 + row * DM))[sl];
        v[i] = make_float4(a.x + (float)bh[0] + (float)b2h[0],
                           a.y + (float)bh[1] + (float)b2h[1],
                           a.z + (float)bh[2] + (float)b2h[2],
                           a.w + (float)bh[3] + (float)b2h[3]);
        s += v[i].x + v[i].y + v[i].z + v[i].w;
    }
#pragma unroll
    for (int off = 32; off; off >>= 1) s += __shfl_xor(s, off);
    float mu = s * (1.0f / 1024.0f);
    float var = 0.f;
#pragma unroll
    for (int i = 0; i < 4; ++i) {
        float dx = v[i].x - mu, dy = v[i].y - mu, dz = v[i].z - mu, dw = v[i].w - mu;
        var += dx * dx + dy * dy + dz * dz + dw * dw;
    }
#pragma unroll
    for (int off = 32; off; off >>= 1) var += __shfl_xor(var, off);
    float rs = 1.0f / sqrtf(var * (1.0f / 1024.0f) + 1e-5f);
    const float4* pg = (const float4*)g;
    const float4* pe = (const float4*)be;
#pragma unroll
    for (int i = 0; i < 4; ++i) {
        float4 gg = pg[i * 64 + lane], ee = pe[i * 64 + lane];
        float4 o = make_float4((v[i].x - mu) * rs * gg.x + ee.x,
                               (v[i].y - mu) * rs * gg.y + ee.y,
                               (v[i].z - mu) * rs * gg.z + ee.z,
                               (v[i].w - mu) * rs * gg.w + ee.w);
        if (outf) ((float4*)(outf + row * DM))[i * 64 + lane] = o;
        if (outh) {
            bf16x4 ho = {(bf16)o.x, (bf16)o.y, (bf16)o.z, (bf16)o.w};
            *(bf16x4*)(outh + row * DM + (i * 64 + lane) * 4) = ho;
        }
    }
}

extern "C" void kernel_launch(void* const* d_in, const int* in_sizes, int n_in,
                              void* d_out, int out_size, void* d_ws, size_t ws_size,
                              hipStream_t stream) {
    const float* x   = (const float*)d_in[0];
    const float* Wq  = (const float*)d_in[1];
    const float* bq  = (const float*)d_in[2];
    const float* Wk  = (const float*)d_in[3];
    const float* bk  = (const float*)d_in[4];
    const float* Wv  = (const float*)d_in[5];
    const float* bv  = (const float*)d_in[6];
    const float* Wo  = (const float*)d_in[7];
    const float* bo  = (const float*)d_in[8];
    const float* W1  = (const float*)d_in[9];
    const float* b1  = (const float*)d_in[10];
    const float* W2  = (const float*)d_in[11];
    const float* b2  = (const float*)d_in[12];
    const float* g1  = (const float*)d_in[13];
    const float* be1 = (const float*)d_in[14];
    const float* g2  = (const float*)d_in[15];
    const float* be2 = (const float*)d_in[16];
    float* out = (float*)d_out;

    char* ws = (char*)d_ws;
    size_t off = 0;
    auto alloc = [&](size_t bytes) {
        void* p = ws + off;
        off += (bytes + 255) & ~(size_t)255;
        return p;
    };
    bf16* xh    = (bf16*)alloc((size_t)NTOK * DM * 2);
    bf16* wqkvt = (bf16*)alloc((size_t)3072 * 1024 * 2);
    bf16* wot   = (bf16*)alloc((size_t)1024 * 1024 * 2);
    bf16* w1t   = (bf16*)alloc((size_t)4096 * 1024 * 2);
    bf16* w2t   = (bf16*)alloc((size_t)1024 * 4096 * 2);
    float* bqkv = (float*)alloc((size_t)3072 * 4);
    bf16* qkv   = (bf16*)alloc((size_t)NTOK * 3072 * 2);
    bf16* vtb   = (bf16*)alloc((size_t)NTOK * DM * 2);
    bf16* attno = (bf16*)alloc((size_t)NTOK * DM * 2);
    bf16* proj0 = (bf16*)alloc((size_t)NTOK * DM * 2);   // split-K partial 0 (bf16)
    bf16* proj1 = (bf16*)alloc((size_t)NTOK * DM * 2);   // split-K partial 1 (bf16)
    bf16* x1h   = (bf16*)alloc((size_t)NTOK * DM * 2);   // LN1 out = FFN1 in = LN2 residual
    bf16* ffh   = (bf16*)qkv; // alias: qkv+vtb dead after attn; 67MB for [8192][4096]

    dim3 tb(32, 8);
    cast_f32_bf16<<<2048, 256, 0, stream>>>(x, xh, (long)NTOK * DM);
    // fused: Wq/Wk/Wv -> wqkvt slices, Wo -> wot (one launch, grid z=4)
    transpose_cast4<<<dim3(32, 32, 4), tb, 0, stream>>>(
        Wq, Wk, Wv, Wo,
        wqkvt, wqkvt + (size_t)1024 * 1024, wqkvt + (size_t)2048 * 1024, wot);
    transpose_cast<<<dim3(128, 32), tb, 0, stream>>>(W1, w1t, 1024, 4096);
    transpose_cast<<<dim3(32, 128), tb, 0, stream>>>(W2, w2t, 4096, 1024);
    concat3<<<12, 256, 0, stream>>>(bq, bk, bv, bqkv);

    // QKV: [8192,1024]@[1024,3072] -> bf16 (BN=192: grid 16x32=512 = 2 even rounds)
    gemm4ph<192><<<dim3(3072 / 192, 8192 / 256, 1), 512, 0, stream>>>(
        xh, wqkvt, bqkv, qkv, 3072, 1024, 1024, 0, 0);
    build_vt<<<dim3(SEQL / 32, 2, 64), tb, 0, stream>>>(qkv, vtb);
    attn_fwd<<<dim3(SEQL / 128, 64), 256, 0, stream>>>(qkv, vtb, attno);
    // Wo: split-K x2 (Klen=512), grid 4x32x2=256 -> bf16 partials proj0/proj1
    gemm4ph<256><<<dim3(1024 / 256, 8192 / 256, 2), 512, 0, stream>>>(
        attno, wot, bo, proj0, 1024, 1024, 512, 0, (long)NTOK * DM);
    add_ln<1><<<NTOK / 4, 256, 0, stream>>>(x, proj0, proj1, g1, be1, nullptr, x1h);
    // FFN1: [8192,1024]@[1024,4096]+ReLU -> bf16 (grid 16x32=512)
    gemm4ph<256><<<dim3(4096 / 256, 8192 / 256, 1), 512, 0, stream>>>(
        x1h, w1t, b1, ffh, 4096, 1024, 1024, 1, 0);
    // FFN2: split-K x2 (Klen=2048), grid 4x32x2=256 -> bf16 partials proj0/proj1
    gemm4ph<256><<<dim3(1024 / 256, 8192 / 256, 2), 512, 0, stream>>>(
        ffh, w2t, b2, proj0, 1024, 4096, 2048, 0, (long)NTOK * DM);
    add_ln<0><<<NTOK / 4, 256, 0, stream>>>(x1h, proj0, proj1, g2, be2, out, nullptr);
}